// Round 1
// baseline (198.171 us; speedup 1.0000x reference)
//
#include <hip/hip_runtime.h>

// msg[b,o,n] = sum_d We[o,d]*e_vw[b,d,n] + sum_d Ww[o,d]*h_w[b,d,n] + be[o]+bw[o]
// B=128, D=768, N=256.  Fused single GEMM: M=768, N=256, K=1536 per batch.
// 128x128 tile, BK=32, 4 waves, mfma_f32_16x16x32_bf16, fp32->bf16 at stage time.

#define DD   768
#define NCOL 256
#define KTOT 1536
#define BM   128
#define BN   128
#define BK   32
#define NIT  48   // KTOT / BK

typedef __bf16 bf16;
typedef __attribute__((ext_vector_type(8))) __bf16 bf16x8;
typedef __attribute__((ext_vector_type(4))) float f32x4;
typedef __attribute__((ext_vector_type(4))) unsigned int u32x4;

// XOR swizzle: row stride 64B, spread 8-row groups across banks (16B granularity).
// Used identically for LDS writes and fragment reads -> consistent scrambled layout.
__device__ __forceinline__ int swz(int row, int kbyte) {
  return (row * 64 + kbyte) ^ ((row & 7) << 4);
}

__global__ __launch_bounds__(256, 2)
void msg_kernel(const float* __restrict__ h_w, const float* __restrict__ e_vw,
                const float* __restrict__ We, const float* __restrict__ be,
                const float* __restrict__ Ww, const float* __restrict__ bw,
                float* __restrict__ out) {
  // buf0: A @0, B @8192 ; buf1: A @16384, B @24576
  __shared__ __align__(16) unsigned char smem[2 * 16384];
  __shared__ float bias_s[BM];

  const int tid = threadIdx.x;
  const int bn0 = blockIdx.x * BN;   // output col base (n)
  const int bm0 = blockIdx.y * BM;   // output row base (o)
  const int bb  = blockIdx.z;        // batch

  if (tid < BM) bias_s[tid] = be[bm0 + tid] + bw[bm0 + tid];

  // ---- staging maps ----
  // A tile (weights): 128 rows x 32 k. thread -> (row, 16-float k-half)
  const int rowA = tid >> 1;
  const int kcA  = tid & 1;
  const float* pWe = We + (size_t)(bm0 + rowA) * DD + kcA * 16;
  const float* pWw = Ww + (size_t)(bm0 + rowA) * DD + kcA * 16;
  const int wA0 = swz(rowA, kcA * 32);
  const int wA1 = swz(rowA, kcA * 32 + 16);

  // B tile (inputs): 32 k x 128 n, stored transposed [n][k]. thread -> (n, k-half)
  const int nB  = tid & 127;
  const int kcB = tid >> 7;
  const float* pe = e_vw + (size_t)bb * DD * NCOL + (size_t)(kcB * 16) * NCOL + bn0 + nB;
  const float* ph = h_w  + (size_t)bb * DD * NCOL + (size_t)(kcB * 16) * NCOL + bn0 + nB;
  const int wB0 = swz(nB, kcB * 32);
  const int wB1 = swz(nB, kcB * 32 + 16);

  float fa[16], fb[16];

  auto load_regs = [&](int it) {
    const float* pa = (it < 24) ? (pWe + it * BK) : (pWw + (it - 24) * BK);
    #pragma unroll
    for (int i = 0; i < 4; ++i) {
      f32x4 v = *(const f32x4*)(pa + 4 * i);
      fa[4*i+0] = v[0]; fa[4*i+1] = v[1]; fa[4*i+2] = v[2]; fa[4*i+3] = v[3];
    }
    const float* pb = (it < 24) ? (pe + (size_t)it * BK * NCOL)
                                : (ph + (size_t)(it - 24) * BK * NCOL);
    #pragma unroll
    for (int i = 0; i < 16; ++i) fb[i] = pb[(size_t)i * NCOL];
  };

  auto store_lds = [&](int buf) {
    unsigned char* base = smem + buf * 16384;
    union { bf16 h[16]; u32x4 q[2]; } ua, ub;
    #pragma unroll
    for (int i = 0; i < 16; ++i) ua.h[i] = (bf16)fa[i];
    #pragma unroll
    for (int i = 0; i < 16; ++i) ub.h[i] = (bf16)fb[i];
    *(u32x4*)(base + wA0) = ua.q[0];
    *(u32x4*)(base + wA1) = ua.q[1];
    *(u32x4*)(base + 8192 + wB0) = ub.q[0];
    *(u32x4*)(base + 8192 + wB1) = ub.q[1];
  };

  // ---- compute maps ----
  const int lane = tid & 63;
  const int wid  = tid >> 6;       // 4 waves: 2(m) x 2(n)
  const int wm = wid >> 1, wn = wid & 1;
  const int lr  = lane & 15;
  const int kch = (lane >> 4) * 16;   // k-chunk byte offset (8 bf16)

  f32x4 acc[4][4] = {};

  auto compute = [&](int buf) {
    const unsigned char* base = smem + buf * 16384;
    bf16x8 af[4], bfr[4];
    #pragma unroll
    for (int m = 0; m < 4; ++m)
      af[m] = *(const bf16x8*)(base + swz(wm * 64 + m * 16 + lr, kch));
    #pragma unroll
    for (int n = 0; n < 4; ++n)
      bfr[n] = *(const bf16x8*)(base + 8192 + swz(wn * 64 + n * 16 + lr, kch));
    #pragma unroll
    for (int m = 0; m < 4; ++m)
      #pragma unroll
      for (int n = 0; n < 4; ++n)
        acc[m][n] = __builtin_amdgcn_mfma_f32_16x16x32_bf16(af[m], bfr[n], acc[m][n], 0, 0, 0);
  };

  // ---- main loop: double-buffered, 1 barrier per K-step ----
  load_regs(0);
  store_lds(0);
  __syncthreads();
  for (int it = 0; it < NIT - 1; ++it) {
    load_regs(it + 1);            // issue next-tile global loads early
    compute(it & 1);
    store_lds((it + 1) & 1);      // other buffer: no conflict with readers
    __syncthreads();
  }
  compute((NIT - 1) & 1);

  // ---- epilogue: bias + store. C/D layout: col=lane&15, row=(lane>>4)*4+reg ----
  float* po = out + (size_t)bb * DD * NCOL;
  const int g4 = (lane >> 4) * 4;
  #pragma unroll
  for (int m = 0; m < 4; ++m) {
    const int r0 = wm * 64 + m * 16 + g4;
    #pragma unroll
    for (int n = 0; n < 4; ++n) {
      const int col = bn0 + wn * 64 + n * 16 + lr;
      #pragma unroll
      for (int j = 0; j < 4; ++j)
        po[(size_t)(bm0 + r0 + j) * NCOL + col] = acc[m][n][j] + bias_s[r0 + j];
    }
  }
}

extern "C" void kernel_launch(void* const* d_in, const int* in_sizes, int n_in,
                              void* d_out, int out_size, void* d_ws, size_t ws_size,
                              hipStream_t stream) {
  // inputs: 0:h_v(unused) 1:h_w 2:e_vw 3:We 4:be 5:Ww 6:bw
  const float* h_w  = (const float*)d_in[1];
  const float* e_vw = (const float*)d_in[2];
  const float* We   = (const float*)d_in[3];
  const float* be   = (const float*)d_in[4];
  const float* Ww   = (const float*)d_in[5];
  const float* bw   = (const float*)d_in[6];
  float* out = (float*)d_out;

  dim3 grid(NCOL / BN, DD / BM, 128);   // (2, 6, 128)
  msg_kernel<<<grid, 256, 0, stream>>>(h_w, e_vw, We, be, Ww, bw, out);
}

// Round 2
// 187.067 us; speedup vs baseline: 1.0594x; 1.0594x over previous
//
#include <hip/hip_runtime.h>

// msg[b,o,n] = sum_d We[o,d]*e_vw[b,d,n] + sum_d Ww[o,d]*h_w[b,d,n] + be[o]+bw[o]
// B=128, D=768, N=256. Fused GEMM: M=768, N=256, K=1536 per batch.
// Pre-kernel: Wcat = [We|Ww] as bf16 [768][1536] in d_ws.
// Main: 128x128 tile, BK=32, 4 waves, mfma_f32_16x16x32_bf16,
//       2-deep B register prefetch, 1-deep A (L2-resident bf16), dbuf LDS.

#define DD   768
#define NCOL 256
#define KTOT 1536
#define BM   128
#define BN   128
#define BK   32
#define NIT  48

typedef __bf16 bf16;
typedef __attribute__((ext_vector_type(8))) __bf16 bf16x8;
typedef __attribute__((ext_vector_type(4))) float f32x4;
typedef __attribute__((ext_vector_type(2))) float f32x2;
typedef __attribute__((ext_vector_type(4))) unsigned int u32x4;

// XOR swizzle on bits 4-6 using row bits 1-3: verified 2-way max for
// frag reads (rows 0..15 consecutive), A writes (rows t>>1, 2 kh),
// B writes (rows 2nb+i, kb per wave).
__device__ __forceinline__ int swz(int row, int kbyte) {
  return (row * 64 + kbyte) ^ (((row >> 1) & 7) << 4);
}

// ---- pre-kernel: Wcat[o][k] bf16 ; k<768 -> We, else Ww ----
__global__ void prep_w(const float* __restrict__ We, const float* __restrict__ Ww,
                       unsigned short* __restrict__ Wcat) {
  int i = blockIdx.x * blockDim.x + threadIdx.x;  // 147456 threads, 8 elems each
  int base = i * 8;
  int o = base / KTOT;
  int k = base % KTOT;
  const float* src = (k < DD) ? (We + (size_t)o * DD + k)
                              : (Ww + (size_t)o * DD + (k - DD));
  f32x4 v0 = *(const f32x4*)src;
  f32x4 v1 = *(const f32x4*)(src + 4);
  union { bf16 h[8]; u32x4 q; } u;
  u.h[0]=(bf16)v0[0]; u.h[1]=(bf16)v0[1]; u.h[2]=(bf16)v0[2]; u.h[3]=(bf16)v0[3];
  u.h[4]=(bf16)v1[0]; u.h[5]=(bf16)v1[1]; u.h[6]=(bf16)v1[2]; u.h[7]=(bf16)v1[3];
  *(u32x4*)(Wcat + (size_t)o * KTOT + k) = u.q;
}

__global__ __launch_bounds__(256, 3)
void msg_kernel(const float* __restrict__ h_w, const float* __restrict__ e_vw,
                const unsigned short* __restrict__ Wcat,
                const float* __restrict__ be, const float* __restrict__ bw,
                float* __restrict__ out) {
  // buf0: A @0, B @8192 ; buf1: A @16384, B @24576
  __shared__ __align__(16) unsigned char smem[2 * 16384];
  __shared__ float bias_s[BM];

  const int tid = threadIdx.x;
  // XCD-chunked swizzle (1536 % 8 == 0, bijective); 6 row-blocks sharing a
  // B panel are consecutive logical ids -> same XCD L2.
  const int b  = blockIdx.x;
  const int lb = (b & 7) * 192 + (b >> 3);
  const int y  = lb % 6;
  const int g  = lb / 6;
  const int bm0 = y * BM;
  const int bn0 = (g & 1) * BN;
  const int bb  = g >> 1;

  if (tid < BM) bias_s[tid] = be[bm0 + tid] + bw[bm0 + tid];

  // ---- A staging map: row = tid>>1, k-half = tid&1 (16 bf16 = 32B) ----
  const int rowA = tid >> 1, kh = tid & 1;
  const unsigned short* pA0 = Wcat + (size_t)(bm0 + rowA) * KTOT + kh * 16;
  const int wA0 = swz(rowA, kh * 32);
  const int wA1 = swz(rowA, kh * 32 + 16);

  // ---- B staging map: 8k x 2n micro-block; nb = tid&63, kb = wave id ----
  const int nb = tid & 63, kbw = tid >> 6;
  const size_t bofs = (size_t)bb * DD * NCOL + (size_t)(kbw * 8) * NCOL + bn0 + nb * 2;
  const float* pE = e_vw + bofs;
  const float* pH = h_w  + bofs;
  const int wB0 = swz(2 * nb,     kbw * 16);
  const int wB1 = swz(2 * nb + 1, kbw * 16);

  u32x4 aR0, aR1;          // A prefetch regs (bf16 bits, no cvt needed)
  float bEr[16], bOr[16];  // B prefetch regs, even/odd tiles (static sets)

  auto issueA = [&](int T) {
    const unsigned short* p = pA0 + T * BK;
    aR0 = *(const u32x4*)p;
    aR1 = *(const u32x4*)(p + 8);
  };
  auto storeA = [&](int buf) {
    unsigned char* base = smem + buf * 16384;
    *(u32x4*)(base + wA0) = aR0;
    *(u32x4*)(base + wA1) = aR1;
  };
  auto issueB = [&](int T, float (&r)[16]) {
    const float* p = (T < 24) ? (pE + (size_t)T * BK * NCOL)
                              : (pH + (size_t)(T - 24) * BK * NCOL);
    #pragma unroll
    for (int kk = 0; kk < 8; ++kk) {
      f32x2 v = *(const f32x2*)(p + (size_t)kk * NCOL);
      r[2 * kk] = v[0]; r[2 * kk + 1] = v[1];
    }
  };
  auto storeB = [&](int buf, const float (&r)[16]) {
    unsigned char* base = smem + buf * 16384 + 8192;
    union { bf16 h[8]; u32x4 q; } r0, r1;
    #pragma unroll
    for (int kk = 0; kk < 8; ++kk) {
      r0.h[kk] = (bf16)r[2 * kk];
      r1.h[kk] = (bf16)r[2 * kk + 1];
    }
    *(u32x4*)(base + wB0) = r0.q;
    *(u32x4*)(base + wB1) = r1.q;
  };

  // ---- compute map: 4 waves 2x2, wave tile 64x64 ----
  const int lane = tid & 63, wid = tid >> 6;
  const int wm = wid >> 1, wn = wid & 1;
  const int lr = lane & 15, kch = (lane >> 4) * 16;
  f32x4 acc[4][4] = {};

  auto compute = [&](int buf) {
    const unsigned char* base = smem + buf * 16384;
    bf16x8 af[4], bfr[4];
    #pragma unroll
    for (int m = 0; m < 4; ++m)
      af[m] = *(const bf16x8*)(base + swz(wm * 64 + m * 16 + lr, kch));
    #pragma unroll
    for (int n = 0; n < 4; ++n)
      bfr[n] = *(const bf16x8*)(base + 8192 + swz(wn * 64 + n * 16 + lr, kch));
    #pragma unroll
    for (int m = 0; m < 4; ++m)
      #pragma unroll
      for (int n = 0; n < 4; ++n)
        acc[m][n] = __builtin_amdgcn_mfma_f32_16x16x32_bf16(af[m], bfr[n], acc[m][n], 0, 0, 0);
  };

  // ---- prologue ----
  issueB(0, bEr);
  issueA(0);
  storeA(0);
  storeB(0, bEr);
  issueB(1, bOr);
  __syncthreads();

  // ---- main loop, unrolled x2 for static reg sets; tiles 0..45 ----
  for (int it = 0; it < 45; it += 2) {
    issueB(it + 2, bEr);     // 2-deep: consumed next sub-step
    issueA(it + 1);          // 1-deep: L2-resident bf16 weights
    compute(0);
    storeA(1); storeB(1, bOr);
    __syncthreads();

    issueB(it + 3, bOr);
    issueA(it + 2);
    compute(1);
    storeA(0); storeB(0, bEr);
    __syncthreads();
  }
  // ---- tail: tiles 46 (in buf0), 47 ----
  issueA(47);
  compute(0);
  storeA(1); storeB(1, bOr);
  __syncthreads();
  compute(1);

  // ---- epilogue: bias + store. C/D: col=lane&15, row=(lane>>4)*4+reg ----
  float* po = out + (size_t)bb * DD * NCOL;
  const int g4 = (lane >> 4) * 4;
  #pragma unroll
  for (int m = 0; m < 4; ++m) {
    const int r0 = wm * 64 + m * 16 + g4;
    #pragma unroll
    for (int n = 0; n < 4; ++n) {
      const int col = bn0 + wn * 64 + n * 16 + lr;
      #pragma unroll
      for (int j = 0; j < 4; ++j)
        po[(size_t)(bm0 + r0 + j) * NCOL + col] = acc[m][n][j] + bias_s[r0 + j];
    }
  }
}

extern "C" void kernel_launch(void* const* d_in, const int* in_sizes, int n_in,
                              void* d_out, int out_size, void* d_ws, size_t ws_size,
                              hipStream_t stream) {
  // inputs: 0:h_v(unused) 1:h_w 2:e_vw 3:We 4:be 5:Ww 6:bw
  const float* h_w  = (const float*)d_in[1];
  const float* e_vw = (const float*)d_in[2];
  const float* We   = (const float*)d_in[3];
  const float* be   = (const float*)d_in[4];
  const float* Ww   = (const float*)d_in[5];
  const float* bw   = (const float*)d_in[6];
  float* out = (float*)d_out;
  unsigned short* Wcat = (unsigned short*)d_ws;  // 768*1536*2 = 2.36 MB

  prep_w<<<dim3(KTOT * DD / 8 / 256), 256, 0, stream>>>(We, Ww, Wcat);
  msg_kernel<<<dim3(1536), 256, 0, stream>>>(h_w, e_vw, Wcat, be, bw, out);
}